// Round 11
// baseline (194.294 us; speedup 1.0000x reference)
//
#include <hip/hip_runtime.h>
#include <hip/hip_bf16.h>

using bf16 = __bf16;
typedef __bf16 bfx8 __attribute__((ext_vector_type(8)));
typedef float  f32x4 __attribute__((ext_vector_type(4)));

static constexpr int Tt = 2048;
static constexpr int Cm = 1024;   // d_model
static constexpr int NH = 16;
static constexpr int DH = 64;
static constexpr int Bb = 4;
static constexpr int BH = Bb * NH;  // 64

__device__ __forceinline__ float fexp2(float x) { return __builtin_amdgcn_exp2f(x); }

__device__ __forceinline__ void gl_lds16(const void* g, void* lds) {
  __builtin_amdgcn_global_load_lds(
      (const __attribute__((address_space(1))) unsigned int*)g,
      (__attribute__((address_space(3))) unsigned int*)lds, 16, 0, 0);
}

// ---------------- cast fp32 -> bf16 (vectorized) ----------------
__global__ void cast_bf16_kernel(const float* __restrict__ in, bf16* __restrict__ out) {
  int i = blockIdx.x * 256 + threadIdx.x;       // each handles 8 elems
  const float4* p = (const float4*)in + (size_t)i * 2;
  float4 a = p[0], b = p[1];
  bfx8 v;
  v[0] = (bf16)a.x; v[1] = (bf16)a.y; v[2] = (bf16)a.z; v[3] = (bf16)a.w;
  v[4] = (bf16)b.x; v[5] = (bf16)b.y; v[6] = (bf16)b.z; v[7] = (bf16)b.w;
  *((bfx8*)out + i) = v;
}

// ---------------- transpose + cast: in[R][C] f32 -> out[C][R] bf16 ----------------
__global__ void transpose_cast_kernel(const float* __restrict__ in, bf16* __restrict__ out,
                                      int R, int C) {
  __shared__ float tile[32][33];
  int c0 = blockIdx.x * 32, r0 = blockIdx.y * 32;
  int tx = threadIdx.x & 31, ty = threadIdx.x >> 5;  // ty 0..7
#pragma unroll
  for (int i = 0; i < 32; i += 8)
    tile[ty + i][tx] = in[(size_t)(r0 + ty + i) * C + c0 + tx];
  __syncthreads();
#pragma unroll
  for (int i = 0; i < 32; i += 8)
    out[(size_t)(c0 + ty + i) * R + r0 + tx] = (bf16)tile[tx][ty + i];
}

// ---------------- GEMM: C[M][N] = A[M][K] @ Bt[N][K]^T + bias ----------------
// Proven single-buffer 2-barrier structure (m97 family / round-7 config).
// WMxWN wave grid, per-wave 64x64 (4x4 acc). BK=64, 128B rows, c^(r&7) swizzle.
// MODE 0: scatter epilogue -> Q(*0.125*log2e), K, V^T.  MODE 1: f32 + bias.
template <int MODE, int BM, int BN, int WM, int WN>
__global__ __launch_bounds__(WM * WN * 64, 2)
void gemm_tile(const bf16* __restrict__ A, const bf16* __restrict__ Bt,
               const float* __restrict__ bias, float* __restrict__ Cf,
               bf16* __restrict__ Qo, bf16* __restrict__ Ko, bf16* __restrict__ Vto,
               int M, int N, int K) {
  constexpr int BKt = 64;
  constexpr int T = WM * WN * 64;
  constexpr int ACH = BM * 8 / T;   // A 16B-chunks per thread
  constexpr int BCH = BN * 8 / T;   // B 16B-chunks per thread
  __shared__ bf16 Al[BM * BKt];
  __shared__ bf16 Bl[BN * BKt];

  const int tid = threadIdx.x;
  const int w = tid >> 6, lane = tid & 63;
  const int lq = lane & 15, lg = lane >> 4;
  const int wm = w / WN, wn = w % WN;
  const int m0 = blockIdx.x * BM, n0 = blockIdx.y * BN;

  f32x4 acc[4][4];
#pragma unroll
  for (int i = 0; i < 4; i++)
#pragma unroll
    for (int j = 0; j < 4; j++) acc[i][j] = (f32x4){0.f, 0.f, 0.f, 0.f};

  for (int k0 = 0; k0 < K; k0 += BKt) {
#pragma unroll
    for (int i = 0; i < ACH; ++i) {
      int j = i * T + tid;
      int r = j >> 3, c = j & 7;
      gl_lds16(A + (size_t)(m0 + r) * K + k0 + ((c ^ (r & 7)) << 3), (char*)Al + j * 16);
    }
#pragma unroll
    for (int i = 0; i < BCH; ++i) {
      int j = i * T + tid;
      int r = j >> 3, c = j & 7;
      gl_lds16(Bt + (size_t)(n0 + r) * K + k0 + ((c ^ (r & 7)) << 3), (char*)Bl + j * 16);
    }
    __syncthreads();
#pragma unroll
    for (int kk = 0; kk < 2; ++kk) {
      bfx8 af[4], bfr[4];
#pragma unroll
      for (int mi = 0; mi < 4; ++mi) {
        int r = wm * 64 + mi * 16 + lq;
        int c = kk * 4 + lg;
        af[mi] = *(const bfx8*)((const char*)Al + r * 128 + ((c ^ (r & 7)) * 16));
      }
#pragma unroll
      for (int ni = 0; ni < 4; ++ni) {
        int r = wn * 64 + ni * 16 + lq;
        int c = kk * 4 + lg;
        bfr[ni] = *(const bfx8*)((const char*)Bl + r * 128 + ((c ^ (r & 7)) * 16));
      }
#pragma unroll
      for (int mi = 0; mi < 4; ++mi)
#pragma unroll
        for (int ni = 0; ni < 4; ++ni)
          acc[mi][ni] = __builtin_amdgcn_mfma_f32_16x16x32_bf16(af[mi], bfr[ni], acc[mi][ni], 0, 0, 0);
    }
    __syncthreads();
  }

  // epilogue: C/D layout col = lane&15, row = (lane>>4)*4 + reg
#pragma unroll
  for (int mi = 0; mi < 4; ++mi) {
#pragma unroll
    for (int ni = 0; ni < 4; ++ni) {
#pragma unroll
      for (int j = 0; j < 4; ++j) {
        int m = m0 + wm * 64 + mi * 16 + lg * 4 + j;
        int n = n0 + wn * 64 + ni * 16 + lq;
        float v = acc[mi][ni][j] + bias[n];
        if constexpr (MODE == 1) {
          Cf[(size_t)m * N + n] = v;
        } else {
          int sel = n >> 10;          // which of q/k/v
          int c1 = n & 1023;
          int hh = c1 >> 6, dd = c1 & 63;
          int bb = m >> 11, t = m & 2047;
          if (sel == 0) {
            // fold softmax scale (1/8) AND log2(e) so attention can use exp2
            Qo[(((size_t)(bb * NH + hh)) * Tt + t) * DH + dd] = (bf16)(v * 0.18033688f);
          } else if (sel == 1) {
            Ko[(((size_t)(bb * NH + hh)) * Tt + t) * DH + dd] = (bf16)v;
          } else {
            Vto[(((size_t)(bb * NH + hh)) * DH + dd) * Tt + t] = (bf16)v;
          }
        }
      }
    }
  }
}

// ---------------- causal flash attention ----------------
// v7: BARRIER-FREE per-wave schedule. KVBLK=32. Each wave owns private LDS
//     (K dbuf + V dbuf + P), stages its own tiles with global_load_lds, syncs
//     only via its own vmcnt(0). 2048 wave-slots, each EXACTLY 65 key-tiles
//     (strip pair {63-slot, slot} at 32-q granularity). No __syncthreads at all.
// Q pre-scaled by 0.125*log2e. Q,K: [bh][t][64]; Vt: [bh][64][t]; O: [b][t][1024] bf16
__global__ __launch_bounds__(256, 2)
void attn_fwd(const bf16* __restrict__ Q, const bf16* __restrict__ K,
              const bf16* __restrict__ Vt, bf16* __restrict__ O) {
  const int w = threadIdx.x >> 6, lane = threadIdx.x & 63;
  const int lq = lane & 15, lg = lane >> 4;

  __shared__ bf16 Klds[4][2][32 * 64];   // per-wave K dbuf (swizzled rows)
  __shared__ bf16 Vlds[4][2][64 * 32];   // per-wave V^T dbuf (linear 64B rows)
  __shared__ bf16 Pl[4][32 * 40];        // per-wave P tile, stride 40 elems
  bf16* Pw = Pl[w];

  bfx8 onesv;
#pragma unroll
  for (int e = 0; e < 8; ++e) onesv[e] = (bf16)1.0f;

  const int gw = blockIdx.x * 4 + w;     // 0..2047
  const int bh = gw >> 5;                // 64 (b,h) pairs
  const int slot = gw & 31;              // 32 slots per bh
  const int b = bh >> 4, h = bh & 15;
  const bf16* Qp = Q + (size_t)bh * Tt * DH;
  const bf16* Kp = K + (size_t)bh * Tt * DH;
  const bf16* Vp = Vt + (size_t)bh * DH * Tt;

  // stage one 32-key tile (K: 32x64 swizzled; V^T: 64x32 linear), 8 loads/lane
#define STG32(buf, tile)                                                         \
  {                                                                              \
    int kk0 = (tile) * 32;                                                       \
    _Pragma("unroll")                                                            \
    for (int i = 0; i < 4; ++i) {                                                \
      int j = i * 64 + lane; int r = j >> 3, c = j & 7;                          \
      gl_lds16(Kp + (size_t)(kk0 + r) * DH + ((c ^ (r & 7)) << 3),               \
               (char*)&Klds[w][buf][0] + j * 16);                                \
    }                                                                            \
    _Pragma("unroll")                                                            \
    for (int i = 0; i < 4; ++i) {                                                \
      int j = i * 64 + lane; int r = j >> 2, c = j & 3;                          \
      gl_lds16(Vp + (size_t)r * Tt + kk0 + (c << 3),                             \
               (char*)&Vlds[w][buf][0] + j * 16);                                \
    }                                                                            \
  }

  for (int rep = 0; rep < 2; ++rep) {
    const int s = rep ? slot : 63 - slot;   // long strip first
    const int q_base = s * 32;              // this wave's 32 q rows
    const int nt = s + 1;                   // 32-key tiles needed (causal)

    // Q fragments: [q-group][d-half]
    bfx8 qf[2][2];
#pragma unroll
    for (int g = 0; g < 2; ++g)
#pragma unroll
      for (int dh = 0; dh < 2; ++dh)
        qf[g][dh] = *(const bfx8*)(Qp + (size_t)(q_base + g * 16 + lq) * DH + dh * 32 + lg * 8);

    f32x4 oacc[2][5];   // [q-group][d-tile 0..3, 4 = row-sum (ones column)]
#pragma unroll
    for (int g = 0; g < 2; ++g)
#pragma unroll
      for (int n = 0; n < 5; ++n) oacc[g][n] = (f32x4){0.f, 0.f, 0.f, 0.f};
    float m_s[2] = {-3e38f, -3e38f};

    STG32(0, 0);
    asm volatile("s_waitcnt vmcnt(0)" ::: "memory");

    int cur = 0;
    for (int t = 0; t < nt; ++t) {
      if (t + 1 < nt) STG32(cur ^ 1, t + 1);   // prefetch flies under this tile's compute

      const char* Kb = (const char*)&Klds[w][cur][0];
      const char* Vb = (const char*)&Vlds[w][cur][0];

      // --- K fragments (swizzled; (cc*16+lq)&7 == lq&7) ---
      bfx8 kf[2][2];
#pragma unroll
      for (int cc = 0; cc < 2; ++cc)
#pragma unroll
        for (int dh = 0; dh < 2; ++dh)
          kf[cc][dh] = *(const bfx8*)(Kb + (cc * 16 + lq) * 128 + (((dh * 4 + lg) ^ (lq & 7)) << 4));

      // --- QK^T: 8 MFMA.  S^T: col = q = lq, row = key = lg*4+reg ---
      f32x4 sv[2][2];
      __builtin_amdgcn_s_setprio(1);
#pragma unroll
      for (int g = 0; g < 2; ++g)
#pragma unroll
        for (int cc = 0; cc < 2; ++cc) {
          f32x4 z = (f32x4){0.f, 0.f, 0.f, 0.f};
          z = __builtin_amdgcn_mfma_f32_16x16x32_bf16(kf[cc][0], qf[g][0], z, 0, 0, 0);
          z = __builtin_amdgcn_mfma_f32_16x16x32_bf16(kf[cc][1], qf[g][1], z, 0, 0, 0);
          sv[g][cc] = z;
        }
      __builtin_amdgcn_s_setprio(0);

      // --- causal mask: only the diagonal tile (t == s) ---
      if (t == nt - 1) {
#pragma unroll
        for (int g = 0; g < 2; ++g) {
          const int q = q_base + g * 16 + lq;
#pragma unroll
          for (int cc = 0; cc < 2; ++cc)
#pragma unroll
            for (int j = 0; j < 4; ++j) {
              int key = t * 32 + cc * 16 + lg * 4 + j;
              if (key > q) sv[g][cc][j] = -3e38f;
            }
        }
      }

      // --- online softmax (exp2 domain; lazy max; ones-column handles sums) ---
#pragma unroll
      for (int g = 0; g < 2; ++g) {
        float lm = -3e38f;
#pragma unroll
        for (int cc = 0; cc < 2; ++cc)
#pragma unroll
          for (int j = 0; j < 4; ++j) lm = fmaxf(lm, sv[g][cc][j]);
        if (__any(lm > m_s[g] + 8.f)) {   // rare: full reduce + rescale
          float pm = fmaxf(lm, __shfl_xor(lm, 16));
          pm = fmaxf(pm, __shfl_xor(pm, 32));
          float mn = fmaxf(m_s[g], pm);
          float fsc = fexp2(m_s[g] - mn);
#pragma unroll
          for (int j = 0; j < 4; ++j) {
            float fq = __shfl(fsc, lg * 4 + j);
#pragma unroll
            for (int n = 0; n < 5; ++n) oacc[g][n][j] *= fq;
          }
          m_s[g] = mn;
        }
#pragma unroll
        for (int cc = 0; cc < 2; ++cc)
#pragma unroll
          for (int j = 0; j < 4; ++j)
            sv[g][cc][j] = fexp2(sv[g][cc][j] - m_s[g]);
        // pack P (row = q-local, col = key-local) -> per-wave LDS
#pragma unroll
        for (int cc = 0; cc < 2; ++cc)
#pragma unroll
          for (int jj = 0; jj < 4; jj += 2) {
            __hip_bfloat162 pr;
            pr.x = __float2bfloat16(sv[g][cc][jj]);
            pr.y = __float2bfloat16(sv[g][cc][jj + 1]);
            *(__hip_bfloat162*)&Pw[(g * 16 + lq) * 40 + cc * 16 + lg * 4 + jj] = pr;
          }
      }

      // --- PV: 8 MFMA + 2 ones-column MFMA (row sums); K-dim = 32 keys ---
      bfx8 pa[2];
#pragma unroll
      for (int g = 0; g < 2; ++g)
        pa[g] = *(const bfx8*)((const char*)Pw + (g * 16 + lq) * 80 + lg * 16);
      __builtin_amdgcn_s_setprio(1);
#pragma unroll
      for (int n = 0; n < 4; ++n) {
        bfx8 vf = *(const bfx8*)(Vb + (n * 16 + lq) * 64 + lg * 16);
#pragma unroll
        for (int g = 0; g < 2; ++g)
          oacc[g][n] = __builtin_amdgcn_mfma_f32_16x16x32_bf16(pa[g], vf, oacc[g][n], 0, 0, 0);
      }
#pragma unroll
      for (int g = 0; g < 2; ++g)
        oacc[g][4] = __builtin_amdgcn_mfma_f32_16x16x32_bf16(pa[g], onesv, oacc[g][4], 0, 0, 0);
      __builtin_amdgcn_s_setprio(0);

      if (t + 1 < nt) asm volatile("s_waitcnt vmcnt(0)" ::: "memory");  // next tile landed
      cur ^= 1;
    }

    // --- normalize + write O[b][t][h*64 + d]; row-sum sits in oacc[g][4][j] ---
#pragma unroll
    for (int g = 0; g < 2; ++g)
#pragma unroll
      for (int j = 0; j < 4; ++j) {
        float linv = 1.f / oacc[g][4][j];
        int tq = q_base + g * 16 + lg * 4 + j;
        size_t base = ((size_t)(b * Tt + tq)) * Cm + h * DH;
#pragma unroll
        for (int n = 0; n < 4; ++n)
          O[base + n * 16 + lq] = (bf16)(oacc[g][n][j] * linv);
      }
  }
#undef STG32
}

extern "C" void kernel_launch(void* const* d_in, const int* in_sizes, int n_in,
                              void* d_out, int out_size, void* d_ws, size_t ws_size,
                              hipStream_t stream) {
  const float* x     = (const float*)d_in[0];
  const float* w_qkv = (const float*)d_in[1];
  const float* b_qkv = (const float*)d_in[2];
  const float* w_out = (const float*)d_in[3];
  const float* b_out = (const float*)d_in[4];
  float* out = (float*)d_out;

  const size_t MT = (size_t)Bb * Tt;  // 8192 rows
  bf16* ws    = (bf16*)d_ws;
  bf16* xb    = ws;                                  // 8Mi elems (x bf16; reused as attn out)
  bf16* attn  = xb;                                  // alias (dead after GEMM1)
  bf16* wqkvT = ws + MT * Cm;                        // 3Mi elems [3072][1024]
  bf16* woutT = wqkvT + (size_t)3 * Cm * Cm;         // 1Mi elems [1024][1024]
  bf16* Qb    = woutT + (size_t)Cm * Cm;             // 8Mi
  bf16* Kb    = Qb + (size_t)BH * Tt * DH;           // 8Mi
  bf16* Vtb   = Kb + (size_t)BH * Tt * DH;           // 8Mi

  cast_bf16_kernel<<<dim3((MT * Cm) / (256 * 8)), 256, 0, stream>>>(x, xb);
  transpose_cast_kernel<<<dim3(3 * Cm / 32, Cm / 32), 256, 0, stream>>>(w_qkv, wqkvT, Cm, 3 * Cm);
  transpose_cast_kernel<<<dim3(Cm / 32, Cm / 32), 256, 0, stream>>>(w_out, woutT, Cm, Cm);

  // QKV: proven round-7 config (128x128, 4 waves, single-buffer); grid 64x24
  gemm_tile<0, 128, 128, 2, 2><<<dim3(MT / 128, (3 * Cm) / 128), 256, 0, stream>>>(
      xb, wqkvT, b_qkv, nullptr, Qb, Kb, Vtb, (int)MT, 3 * Cm, Cm);

  // attn: 512 blocks x 4 independent waves (2048 uniform wave-slots, 65 tiles each)
  attn_fwd<<<dim3(512), 256, 0, stream>>>(Qb, Kb, Vtb, attn);

  // out-proj: proven 128x128 config; grid 64x8
  gemm_tile<1, 128, 128, 2, 2><<<dim3(MT / 128, Cm / 128), 256, 0, stream>>>(
      attn, woutT, b_out, out, nullptr, nullptr, nullptr, (int)MT, Cm, Cm);
}

// Round 12
// 187.335 us; speedup vs baseline: 1.0371x; 1.0371x over previous
//
#include <hip/hip_runtime.h>
#include <hip/hip_bf16.h>

using bf16 = __bf16;
typedef __bf16 bfx8 __attribute__((ext_vector_type(8)));
typedef float  f32x4 __attribute__((ext_vector_type(4)));

static constexpr int Tt = 2048;
static constexpr int Cm = 1024;   // d_model
static constexpr int NH = 16;
static constexpr int DH = 64;
static constexpr int Bb = 4;
static constexpr int BH = Bb * NH;  // 64

__device__ __forceinline__ float fexp2(float x) { return __builtin_amdgcn_exp2f(x); }

__device__ __forceinline__ void gl_lds16(const void* g, void* lds) {
  __builtin_amdgcn_global_load_lds(
      (const __attribute__((address_space(1))) unsigned int*)g,
      (__attribute__((address_space(3))) unsigned int*)lds, 16, 0, 0);
}

// ---------------- fused prep: cast x -> bf16, transpose both weight matrices ----
// blocks [0,4096): cast; [4096,7168): w_qkv^T (C=3072); [7168,8192): w_out^T (C=1024)
__global__ void prep_kernel(const float* __restrict__ x, bf16* __restrict__ xb,
                            const float* __restrict__ w_qkv, bf16* __restrict__ wqkvT,
                            const float* __restrict__ w_out, bf16* __restrict__ woutT) {
  const int bid = blockIdx.x;
  if (bid < 4096) {
    int i = bid * 256 + threadIdx.x;   // 8 elems each
    const float4* p = (const float4*)x + (size_t)i * 2;
    float4 a = p[0], b = p[1];
    bfx8 v;
    v[0] = (bf16)a.x; v[1] = (bf16)a.y; v[2] = (bf16)a.z; v[3] = (bf16)a.w;
    v[4] = (bf16)b.x; v[5] = (bf16)b.y; v[6] = (bf16)b.z; v[7] = (bf16)b.w;
    *((bfx8*)xb + i) = v;
    return;
  }
  const float* in;
  bf16* out;
  int C, t;
  if (bid < 7168) { t = bid - 4096; C = 3072; in = w_qkv; out = wqkvT; }
  else            { t = bid - 7168; C = 1024; in = w_out; out = woutT; }
  const int R = 1024;
  const int nbx = C / 32;
  const int c0 = (t % nbx) * 32, r0 = (t / nbx) * 32;
  __shared__ float tile[32][33];
  int tx = threadIdx.x & 31, ty = threadIdx.x >> 5;  // ty 0..7
#pragma unroll
  for (int i = 0; i < 32; i += 8)
    tile[ty + i][tx] = in[(size_t)(r0 + ty + i) * C + c0 + tx];
  __syncthreads();
#pragma unroll
  for (int i = 0; i < 32; i += 8)
    out[(size_t)(c0 + ty + i) * R + r0 + tx] = (bf16)tile[tx][ty + i];
}

// ---------------- GEMM: C[M][N] = A[M][K] @ Bt[N][K]^T + bias ----------------
// Proven single-buffer 2-barrier structure (m97 family / round-7 config).
// WMxWN wave grid, per-wave 64x64 (4x4 acc). BK=64, 128B rows, c^(r&7) swizzle.
// MODE 0: scatter epilogue -> Q(*0.125*log2e), K, V^T.  MODE 1: f32 + bias.
template <int MODE, int BM, int BN, int WM, int WN>
__global__ __launch_bounds__(WM * WN * 64, 2)
void gemm_tile(const bf16* __restrict__ A, const bf16* __restrict__ Bt,
               const float* __restrict__ bias, float* __restrict__ Cf,
               bf16* __restrict__ Qo, bf16* __restrict__ Ko, bf16* __restrict__ Vto,
               int M, int N, int K) {
  constexpr int BKt = 64;
  constexpr int T = WM * WN * 64;
  constexpr int ACH = BM * 8 / T;   // A 16B-chunks per thread
  constexpr int BCH = BN * 8 / T;   // B 16B-chunks per thread
  __shared__ bf16 Al[BM * BKt];
  __shared__ bf16 Bl[BN * BKt];

  const int tid = threadIdx.x;
  const int w = tid >> 6, lane = tid & 63;
  const int lq = lane & 15, lg = lane >> 4;
  const int wm = w / WN, wn = w % WN;
  const int m0 = blockIdx.x * BM, n0 = blockIdx.y * BN;

  f32x4 acc[4][4];
#pragma unroll
  for (int i = 0; i < 4; i++)
#pragma unroll
    for (int j = 0; j < 4; j++) acc[i][j] = (f32x4){0.f, 0.f, 0.f, 0.f};

  for (int k0 = 0; k0 < K; k0 += BKt) {
#pragma unroll
    for (int i = 0; i < ACH; ++i) {
      int j = i * T + tid;
      int r = j >> 3, c = j & 7;
      gl_lds16(A + (size_t)(m0 + r) * K + k0 + ((c ^ (r & 7)) << 3), (char*)Al + j * 16);
    }
#pragma unroll
    for (int i = 0; i < BCH; ++i) {
      int j = i * T + tid;
      int r = j >> 3, c = j & 7;
      gl_lds16(Bt + (size_t)(n0 + r) * K + k0 + ((c ^ (r & 7)) << 3), (char*)Bl + j * 16);
    }
    __syncthreads();
#pragma unroll
    for (int kk = 0; kk < 2; ++kk) {
      bfx8 af[4], bfr[4];
#pragma unroll
      for (int mi = 0; mi < 4; ++mi) {
        int r = wm * 64 + mi * 16 + lq;
        int c = kk * 4 + lg;
        af[mi] = *(const bfx8*)((const char*)Al + r * 128 + ((c ^ (r & 7)) * 16));
      }
#pragma unroll
      for (int ni = 0; ni < 4; ++ni) {
        int r = wn * 64 + ni * 16 + lq;
        int c = kk * 4 + lg;
        bfr[ni] = *(const bfx8*)((const char*)Bl + r * 128 + ((c ^ (r & 7)) * 16));
      }
#pragma unroll
      for (int mi = 0; mi < 4; ++mi)
#pragma unroll
        for (int ni = 0; ni < 4; ++ni)
          acc[mi][ni] = __builtin_amdgcn_mfma_f32_16x16x32_bf16(af[mi], bfr[ni], acc[mi][ni], 0, 0, 0);
    }
    __syncthreads();
  }

  // epilogue: C/D layout col = lane&15, row = (lane>>4)*4 + reg
#pragma unroll
  for (int mi = 0; mi < 4; ++mi) {
#pragma unroll
    for (int ni = 0; ni < 4; ++ni) {
#pragma unroll
      for (int j = 0; j < 4; ++j) {
        int m = m0 + wm * 64 + mi * 16 + lg * 4 + j;
        int n = n0 + wn * 64 + ni * 16 + lq;
        float v = acc[mi][ni][j] + bias[n];
        if constexpr (MODE == 1) {
          Cf[(size_t)m * N + n] = v;
        } else {
          int sel = n >> 10;          // which of q/k/v
          int c1 = n & 1023;
          int hh = c1 >> 6, dd = c1 & 63;
          int bb = m >> 11, t = m & 2047;
          if (sel == 0) {
            // fold softmax scale (1/8) AND log2(e) so attention can use exp2
            Qo[(((size_t)(bb * NH + hh)) * Tt + t) * DH + dd] = (bf16)(v * 0.18033688f);
          } else if (sel == 1) {
            Ko[(((size_t)(bb * NH + hh)) * Tt + t) * DH + dd] = (bf16)v;
          } else {
            Vto[(((size_t)(bb * NH + hh)) * DH + dd) * Tt + t] = (bf16)v;
          }
        }
      }
    }
  }
}

// ---------------- causal flash attention ----------------
// v8: round-7 v6 structure (512 blocks, exact-uniform strip pairs, shared staged K)
//     MINUS V staging: V^T read direct from global (L2-resident per XCD; m169),
//     issued EARLY (right after QK MFMAs) so L2 latency hides under softmax.
// Q pre-scaled by 0.125*log2e. Q,K: [bh][t][64]; Vt: [bh][64][t]; O: [b][t][1024] bf16
__global__ __launch_bounds__(256, 2)
void attn_fwd(const bf16* __restrict__ Q, const bf16* __restrict__ K,
              const bf16* __restrict__ Vt, bf16* __restrict__ O) {
  const int w = threadIdx.x >> 6, lane = threadIdx.x & 63;
  const int lq = lane & 15, lg = lane >> 4;
  const int tid = threadIdx.x;

  __shared__ bf16 Klds[2][64][64];   // double-buffered K tile (swizzled content)
  __shared__ bf16 Pl[4][32 * 72];    // per-wave P^T tile, stride 72 (16B-aligned rows)
  bf16* Pw = Pl[w];

  bfx8 onesv;
#pragma unroll
  for (int e = 0; e < 8; ++e) onesv[e] = (bf16)1.0f;

  const int cls = blockIdx.x >> 6;   // 0..7
  const int bh = blockIdx.x & 63;
  const int b = bh >> 4, h = bh & 15;
  const bf16* Qp = Q + (size_t)bh * Tt * DH;
  const bf16* Kp = K + (size_t)bh * Tt * DH;
  const bf16* Vp = Vt + (size_t)bh * DH * Tt;

  for (int rep = 0; rep < 2; ++rep) {
    const int strip = rep ? cls : 15 - cls;    // long item first
    const int q_base = strip * 128 + w * 32;   // this wave's 32 q rows

    // Q fragments: [q-group][d-half]
    bfx8 qf[2][2];
#pragma unroll
    for (int g = 0; g < 2; ++g)
#pragma unroll
      for (int dh = 0; dh < 2; ++dh)
        qf[g][dh] = *(const bfx8*)(Qp + (size_t)(q_base + g * 16 + lq) * DH + dh * 32 + lg * 8);

    f32x4 oacc[2][5];   // [q-group][d-tile 0..3, 4 = row-sum (ones column)]
#pragma unroll
    for (int g = 0; g < 2; ++g)
#pragma unroll
      for (int n = 0; n < 5; ++n) oacc[g][n] = (f32x4){0.f, 0.f, 0.f, 0.f};
    float m_s[2] = {-3e38f, -3e38f};

    const int kend_w = q_base + 32;          // this wave's causal bound
    const int nt = 2 * (strip + 1);          // block-level #64-key tiles

    // stage K tile only: 512 16B chunks; inverse-swizzled source, linear LDS dest
#define STAGE_K(buf, tile)                                                       \
  {                                                                              \
    int kk0 = (tile) * 64;                                                       \
    _Pragma("unroll")                                                            \
    for (int i = 0; i < 2; ++i) {                                                \
      int j = i * 256 + tid;                                                     \
      int r = j >> 3, c8 = j & 7;                                                \
      int cs8 = (c8 ^ (r & 7)) << 3;                                             \
      gl_lds16(Kp + (size_t)(kk0 + r) * DH + cs8, (char*)Klds[buf] + j * 16);    \
    }                                                                            \
  }

    STAGE_K(0, 0);
    __syncthreads();

    for (int t = 0; t < nt; ++t) {
      const int k0 = t * 64;
      const int cur = t & 1;
      if (t + 1 < nt) STAGE_K(cur ^ 1, t + 1);

      if (k0 < kend_w) {
        // --- K fragments from LDS (swizzled; (cc*16+lq)&7 == lq&7) ---
        bfx8 kf[4][2];
#pragma unroll
        for (int cc = 0; cc < 4; ++cc)
#pragma unroll
          for (int dh = 0; dh < 2; ++dh)
            kf[cc][dh] = *(const bfx8*)&Klds[cur][cc * 16 + lq][((dh * 4 + lg) ^ (lq & 7)) << 3];

        // --- QK^T: 16 MFMA ---
        f32x4 s[2][4];
        __builtin_amdgcn_s_setprio(1);
#pragma unroll
        for (int g = 0; g < 2; ++g)
#pragma unroll
          for (int cc = 0; cc < 4; ++cc) {
            f32x4 z = (f32x4){0.f, 0.f, 0.f, 0.f};
            z = __builtin_amdgcn_mfma_f32_16x16x32_bf16(kf[cc][0], qf[g][0], z, 0, 0, 0);
            z = __builtin_amdgcn_mfma_f32_16x16x32_bf16(kf[cc][1], qf[g][1], z, 0, 0, 0);
            s[g][cc] = z;
          }
        __builtin_amdgcn_s_setprio(0);

        // --- early-issue V^T loads (direct from global/L2); land during softmax ---
        bfx8 vf[2][4];
#pragma unroll
        for (int c = 0; c < 2; ++c)
#pragma unroll
          for (int n = 0; n < 4; ++n)
            vf[c][n] = *(const bfx8*)(Vp + (size_t)(n * 16 + lq) * Tt + k0 + c * 32 + lg * 8);

        const bool diag = (k0 + 64 > q_base);
        // --- online softmax (exp2 domain; lazy max, ones-column handles sums) ---
#pragma unroll
        for (int g = 0; g < 2; ++g) {
          const int q = q_base + g * 16 + lq;
          if (diag) {
#pragma unroll
            for (int cc = 0; cc < 4; ++cc)
#pragma unroll
              for (int j = 0; j < 4; ++j) {
                int key = k0 + cc * 16 + lg * 4 + j;
                if (key > q) s[g][cc][j] = -3e38f;
              }
          }
          float lm = -3e38f;
#pragma unroll
          for (int cc = 0; cc < 4; ++cc)
#pragma unroll
            for (int j = 0; j < 4; ++j) lm = fmaxf(lm, s[g][cc][j]);
          if (__any(lm > m_s[g] + 8.f)) {   // rare: full reduce + rescale
            float pm = fmaxf(lm, __shfl_xor(lm, 16));
            pm = fmaxf(pm, __shfl_xor(pm, 32));
            float mn = fmaxf(m_s[g], pm);
            float fsc = fexp2(m_s[g] - mn);
#pragma unroll
            for (int j = 0; j < 4; ++j) {
              float fq = __shfl(fsc, lg * 4 + j);
#pragma unroll
              for (int n = 0; n < 5; ++n) oacc[g][n][j] *= fq;
            }
            m_s[g] = mn;
          }
#pragma unroll
          for (int cc = 0; cc < 4; ++cc)
#pragma unroll
            for (int j = 0; j < 4; ++j)
              s[g][cc][j] = fexp2(s[g][cc][j] - m_s[g]);
          // pack P^T -> per-wave LDS
#pragma unroll
          for (int cc = 0; cc < 4; ++cc)
#pragma unroll
            for (int jj = 0; jj < 4; jj += 2) {
              __hip_bfloat162 pr;
              pr.x = __float2bfloat16(s[g][cc][jj]);
              pr.y = __float2bfloat16(s[g][cc][jj + 1]);
              *(__hip_bfloat162*)&Pw[(g * 16 + lq) * 72 + cc * 16 + lg * 4 + jj] = pr;
            }
        }

        // --- PV: 16 MFMA + 4 ones-column MFMA (row sums) ---
#pragma unroll
        for (int c = 0; c < 2; ++c) {
          bfx8 pa[2];
#pragma unroll
          for (int g = 0; g < 2; ++g)
            pa[g] = *(const bfx8*)&Pw[(g * 16 + lq) * 72 + c * 32 + lg * 8];
          __builtin_amdgcn_s_setprio(1);
#pragma unroll
          for (int n = 0; n < 4; ++n)
#pragma unroll
            for (int g = 0; g < 2; ++g)
              oacc[g][n] = __builtin_amdgcn_mfma_f32_16x16x32_bf16(pa[g], vf[c][n], oacc[g][n], 0, 0, 0);
#pragma unroll
          for (int g = 0; g < 2; ++g)
            oacc[g][4] = __builtin_amdgcn_mfma_f32_16x16x32_bf16(pa[g], onesv, oacc[g][4], 0, 0, 0);
          __builtin_amdgcn_s_setprio(0);
        }
      }
      __syncthreads();   // drains staging vmcnt; publishes next K tile
    }

    // --- normalize + write O[b][t][h*64 + d]; row-sum sits in oacc[g][4][j] ---
#pragma unroll
    for (int g = 0; g < 2; ++g)
#pragma unroll
      for (int j = 0; j < 4; ++j) {
        float linv = 1.f / oacc[g][4][j];
        int t = q_base + g * 16 + lg * 4 + j;
        size_t base = ((size_t)(b * Tt + t)) * Cm + h * DH;
#pragma unroll
        for (int n = 0; n < 4; ++n)
          O[base + n * 16 + lq] = (bf16)(oacc[g][n][j] * linv);
      }
    __syncthreads();   // LDS safe for next item's staging
#undef STAGE_K
  }
}

extern "C" void kernel_launch(void* const* d_in, const int* in_sizes, int n_in,
                              void* d_out, int out_size, void* d_ws, size_t ws_size,
                              hipStream_t stream) {
  const float* x     = (const float*)d_in[0];
  const float* w_qkv = (const float*)d_in[1];
  const float* b_qkv = (const float*)d_in[2];
  const float* w_out = (const float*)d_in[3];
  const float* b_out = (const float*)d_in[4];
  float* out = (float*)d_out;

  const size_t MT = (size_t)Bb * Tt;  // 8192 rows
  bf16* ws    = (bf16*)d_ws;
  bf16* xb    = ws;                                  // 8Mi elems (x bf16; reused as attn out)
  bf16* attn  = xb;                                  // alias (dead after GEMM1)
  bf16* wqkvT = ws + MT * Cm;                        // 3Mi elems [3072][1024]
  bf16* woutT = wqkvT + (size_t)3 * Cm * Cm;         // 1Mi elems [1024][1024]
  bf16* Qb    = woutT + (size_t)Cm * Cm;             // 8Mi
  bf16* Kb    = Qb + (size_t)BH * Tt * DH;           // 8Mi
  bf16* Vtb   = Kb + (size_t)BH * Tt * DH;           // 8Mi

  // fused prep: cast (4096 blocks) + w_qkv^T (3072) + w_out^T (1024)
  prep_kernel<<<dim3(8192), 256, 0, stream>>>(x, xb, w_qkv, wqkvT, w_out, woutT);

  // QKV: proven round-7 config (128x128, 4 waves, single-buffer); grid 64x24
  gemm_tile<0, 128, 128, 2, 2><<<dim3(MT / 128, (3 * Cm) / 128), 256, 0, stream>>>(
      xb, wqkvT, b_qkv, nullptr, Qb, Kb, Vtb, (int)MT, 3 * Cm, Cm);

  // attn: 512 blocks, exact-uniform strip pairs; K staged, V direct
  attn_fwd<<<dim3(512), 256, 0, stream>>>(Qb, Kb, Vtb, attn);

  // out-proj: proven 128x128 config; grid 64x8
  gemm_tile<1, 128, 128, 2, 2><<<dim3(MT / 128, Cm / 128), 256, 0, stream>>>(
      attn, woutT, b_out, out, nullptr, nullptr, nullptr, (int)MT, Cm, Cm);
}

// Round 13
// 164.888 us; speedup vs baseline: 1.1783x; 1.1361x over previous
//
#include <hip/hip_runtime.h>
#include <hip/hip_bf16.h>

using bf16 = __bf16;
typedef __bf16 bfx8 __attribute__((ext_vector_type(8)));
typedef float  f32x4 __attribute__((ext_vector_type(4)));

static constexpr int Tt = 2048;
static constexpr int Cm = 1024;   // d_model
static constexpr int NH = 16;
static constexpr int DH = 64;
static constexpr int Bb = 4;
static constexpr int BH = Bb * NH;  // 64

__device__ __forceinline__ float fexp2(float x) { return __builtin_amdgcn_exp2f(x); }

__device__ __forceinline__ void gl_lds16(const void* g, void* lds) {
  __builtin_amdgcn_global_load_lds(
      (const __attribute__((address_space(1))) unsigned int*)g,
      (__attribute__((address_space(3))) unsigned int*)lds, 16, 0, 0);
}

// ---------------- fused prep: cast x -> bf16, transpose both weight matrices ----
// blocks [0,4096): cast; [4096,7168): w_qkv^T (C=3072); [7168,8192): w_out^T (C=1024)
__global__ void prep_kernel(const float* __restrict__ x, bf16* __restrict__ xb,
                            const float* __restrict__ w_qkv, bf16* __restrict__ wqkvT,
                            const float* __restrict__ w_out, bf16* __restrict__ woutT) {
  const int bid = blockIdx.x;
  if (bid < 4096) {
    int i = bid * 256 + threadIdx.x;   // 8 elems each
    const float4* p = (const float4*)x + (size_t)i * 2;
    float4 a = p[0], b = p[1];
    bfx8 v;
    v[0] = (bf16)a.x; v[1] = (bf16)a.y; v[2] = (bf16)a.z; v[3] = (bf16)a.w;
    v[4] = (bf16)b.x; v[5] = (bf16)b.y; v[6] = (bf16)b.z; v[7] = (bf16)b.w;
    *((bfx8*)xb + i) = v;
    return;
  }
  const float* in;
  bf16* out;
  int C, t;
  if (bid < 7168) { t = bid - 4096; C = 3072; in = w_qkv; out = wqkvT; }
  else            { t = bid - 7168; C = 1024; in = w_out; out = woutT; }
  const int R = 1024;
  const int nbx = C / 32;
  const int c0 = (t % nbx) * 32, r0 = (t / nbx) * 32;
  __shared__ float tile[32][33];
  int tx = threadIdx.x & 31, ty = threadIdx.x >> 5;  // ty 0..7
#pragma unroll
  for (int i = 0; i < 32; i += 8)
    tile[ty + i][tx] = in[(size_t)(r0 + ty + i) * C + c0 + tx];
  __syncthreads();
#pragma unroll
  for (int i = 0; i < 32; i += 8)
    out[(size_t)(c0 + ty + i) * R + r0 + tx] = (bf16)tile[tx][ty + i];
}

// ---------------- GEMM: C[M][N] = A[M][K] @ Bt[N][K]^T + bias ----------------
// Proven single-buffer 2-barrier structure (m97 family / round-7 config).
// WMxWN wave grid, per-wave 64x64 (4x4 acc). BK=64, 128B rows, c^(r&7) swizzle.
// MODE 0: scatter epilogue -> Q(*0.125*log2e), K, V^T.  MODE 1: f32 + bias.
template <int MODE, int BM, int BN, int WM, int WN>
__global__ __launch_bounds__(WM * WN * 64, 2)
void gemm_tile(const bf16* __restrict__ A, const bf16* __restrict__ Bt,
               const float* __restrict__ bias, float* __restrict__ Cf,
               bf16* __restrict__ Qo, bf16* __restrict__ Ko, bf16* __restrict__ Vto,
               int M, int N, int K) {
  constexpr int BKt = 64;
  constexpr int T = WM * WN * 64;
  constexpr int ACH = BM * 8 / T;   // A 16B-chunks per thread
  constexpr int BCH = BN * 8 / T;   // B 16B-chunks per thread
  __shared__ bf16 Al[BM * BKt];
  __shared__ bf16 Bl[BN * BKt];

  const int tid = threadIdx.x;
  const int w = tid >> 6, lane = tid & 63;
  const int lq = lane & 15, lg = lane >> 4;
  const int wm = w / WN, wn = w % WN;
  const int m0 = blockIdx.x * BM, n0 = blockIdx.y * BN;

  f32x4 acc[4][4];
#pragma unroll
  for (int i = 0; i < 4; i++)
#pragma unroll
    for (int j = 0; j < 4; j++) acc[i][j] = (f32x4){0.f, 0.f, 0.f, 0.f};

  for (int k0 = 0; k0 < K; k0 += BKt) {
#pragma unroll
    for (int i = 0; i < ACH; ++i) {
      int j = i * T + tid;
      int r = j >> 3, c = j & 7;
      gl_lds16(A + (size_t)(m0 + r) * K + k0 + ((c ^ (r & 7)) << 3), (char*)Al + j * 16);
    }
#pragma unroll
    for (int i = 0; i < BCH; ++i) {
      int j = i * T + tid;
      int r = j >> 3, c = j & 7;
      gl_lds16(Bt + (size_t)(n0 + r) * K + k0 + ((c ^ (r & 7)) << 3), (char*)Bl + j * 16);
    }
    __syncthreads();
#pragma unroll
    for (int kk = 0; kk < 2; ++kk) {
      bfx8 af[4], bfr[4];
#pragma unroll
      for (int mi = 0; mi < 4; ++mi) {
        int r = wm * 64 + mi * 16 + lq;
        int c = kk * 4 + lg;
        af[mi] = *(const bfx8*)((const char*)Al + r * 128 + ((c ^ (r & 7)) * 16));
      }
#pragma unroll
      for (int ni = 0; ni < 4; ++ni) {
        int r = wn * 64 + ni * 16 + lq;
        int c = kk * 4 + lg;
        bfr[ni] = *(const bfx8*)((const char*)Bl + r * 128 + ((c ^ (r & 7)) * 16));
      }
#pragma unroll
      for (int mi = 0; mi < 4; ++mi)
#pragma unroll
        for (int ni = 0; ni < 4; ++ni)
          acc[mi][ni] = __builtin_amdgcn_mfma_f32_16x16x32_bf16(af[mi], bfr[ni], acc[mi][ni], 0, 0, 0);
    }
    __syncthreads();
  }

  // epilogue: C/D layout col = lane&15, row = (lane>>4)*4 + reg
#pragma unroll
  for (int mi = 0; mi < 4; ++mi) {
#pragma unroll
    for (int ni = 0; ni < 4; ++ni) {
#pragma unroll
      for (int j = 0; j < 4; ++j) {
        int m = m0 + wm * 64 + mi * 16 + lg * 4 + j;
        int n = n0 + wn * 64 + ni * 16 + lq;
        float v = acc[mi][ni][j] + bias[n];
        if constexpr (MODE == 1) {
          Cf[(size_t)m * N + n] = v;
        } else {
          int sel = n >> 10;          // which of q/k/v
          int c1 = n & 1023;
          int hh = c1 >> 6, dd = c1 & 63;
          int bb = m >> 11, t = m & 2047;
          if (sel == 0) {
            // fold softmax scale (1/8) AND log2(e) so attention can use exp2
            Qo[(((size_t)(bb * NH + hh)) * Tt + t) * DH + dd] = (bf16)(v * 0.18033688f);
          } else if (sel == 1) {
            Ko[(((size_t)(bb * NH + hh)) * Tt + t) * DH + dd] = (bf16)v;
          } else {
            Vto[(((size_t)(bb * NH + hh)) * DH + dd) * Tt + t] = (bf16)v;
          }
        }
      }
    }
  }
}

// ---------------- causal flash attention ----------------
// v6 (round-7 champion): EXACT-uniform persistent schedule: 512 blocks,
//     class c = blockIdx>>6, each block runs strip pair {15-c, c} for its bh
//     -> every block 34 tiles, every CU exactly 2 blocks. K AND V staged in
//     LDS (double-buffered, global_load_lds, XOR-swizzled); one barrier pair
//     per tile; l_s via ones-column MFMA; lazy max; exp2 softmax.
// Q pre-scaled by 0.125*log2e. Q,K: [bh][t][64]; Vt: [bh][64][t]; O: [b][t][1024] bf16
__global__ __launch_bounds__(256, 2)
void attn_fwd(const bf16* __restrict__ Q, const bf16* __restrict__ K,
              const bf16* __restrict__ Vt, bf16* __restrict__ O) {
  const int w = threadIdx.x >> 6, lane = threadIdx.x & 63;
  const int lq = lane & 15, lg = lane >> 4;
  const int tid = threadIdx.x;

  __shared__ bf16 Klds[2][64][64];   // double-buffered K tile (swizzled content)
  __shared__ bf16 Vlds[2][64][64];   // double-buffered V^T tile (swizzled content)
  __shared__ bf16 Pl[4][32 * 72];    // per-wave P^T tile, stride 72 (16B-aligned rows)
  bf16* Pw = Pl[w];

  bfx8 onesv;
#pragma unroll
  for (int e = 0; e < 8; ++e) onesv[e] = (bf16)1.0f;

  const int cls = blockIdx.x >> 6;   // 0..7
  const int bh = blockIdx.x & 63;
  const int b = bh >> 4, h = bh & 15;
  const bf16* Qp = Q + (size_t)bh * Tt * DH;
  const bf16* Kp = K + (size_t)bh * Tt * DH;
  const bf16* Vp = Vt + (size_t)bh * DH * Tt;

  for (int rep = 0; rep < 2; ++rep) {
    const int strip = rep ? cls : 15 - cls;    // long item first
    const int q_base = strip * 128 + w * 32;   // this wave's 32 q rows

    // Q fragments: [q-group][d-half]
    bfx8 qf[2][2];
#pragma unroll
    for (int g = 0; g < 2; ++g)
#pragma unroll
      for (int dh = 0; dh < 2; ++dh)
        qf[g][dh] = *(const bfx8*)(Qp + (size_t)(q_base + g * 16 + lq) * DH + dh * 32 + lg * 8);

    f32x4 oacc[2][5];   // [q-group][d-tile 0..3, 4 = row-sum (ones column)]
#pragma unroll
    for (int g = 0; g < 2; ++g)
#pragma unroll
      for (int n = 0; n < 5; ++n) oacc[g][n] = (f32x4){0.f, 0.f, 0.f, 0.f};
    float m_s[2] = {-3e38f, -3e38f};

    const int kend_w = q_base + 32;          // this wave's causal bound
    const int nt = 2 * (strip + 1);          // block-level #64-key tiles

    // stage K and V tiles: 512 16B chunks each; chunk j -> r=j>>3, c8=j&7,
    // source col8 = c8^(r&7) (inverse-swizzled source, linear LDS dest)
#define STAGE_KV(buf, tile)                                                      \
  {                                                                              \
    int kk0 = (tile) * 64;                                                       \
    _Pragma("unroll")                                                            \
    for (int i = 0; i < 2; ++i) {                                                \
      int j = i * 256 + tid;                                                     \
      int r = j >> 3, c8 = j & 7;                                                \
      int cs8 = (c8 ^ (r & 7)) << 3;                                             \
      gl_lds16(Kp + (size_t)(kk0 + r) * DH + cs8, (char*)Klds[buf] + j * 16);    \
      gl_lds16(Vp + (size_t)r * Tt + kk0 + cs8, (char*)Vlds[buf] + j * 16);      \
    }                                                                            \
  }

    STAGE_KV(0, 0);
    __syncthreads();

    for (int t = 0; t < nt; ++t) {
      const int k0 = t * 64;
      const int cur = t & 1;
      if (t + 1 < nt) STAGE_KV(cur ^ 1, t + 1);

      if (k0 < kend_w) {
        // --- K fragments from LDS (swizzled; (cc*16+lq)&7 == lq&7) ---
        bfx8 kf[4][2];
#pragma unroll
        for (int cc = 0; cc < 4; ++cc)
#pragma unroll
          for (int dh = 0; dh < 2; ++dh)
            kf[cc][dh] = *(const bfx8*)&Klds[cur][cc * 16 + lq][((dh * 4 + lg) ^ (lq & 7)) << 3];

        // --- QK^T: 16 MFMA ---
        f32x4 s[2][4];
        __builtin_amdgcn_s_setprio(1);
#pragma unroll
        for (int g = 0; g < 2; ++g)
#pragma unroll
          for (int cc = 0; cc < 4; ++cc) {
            f32x4 z = (f32x4){0.f, 0.f, 0.f, 0.f};
            z = __builtin_amdgcn_mfma_f32_16x16x32_bf16(kf[cc][0], qf[g][0], z, 0, 0, 0);
            z = __builtin_amdgcn_mfma_f32_16x16x32_bf16(kf[cc][1], qf[g][1], z, 0, 0, 0);
            s[g][cc] = z;
          }
        __builtin_amdgcn_s_setprio(0);

        const bool diag = (k0 + 64 > q_base);
        // --- online softmax (exp2 domain; lazy max, ones-column handles sums) ---
#pragma unroll
        for (int g = 0; g < 2; ++g) {
          const int q = q_base + g * 16 + lq;
          if (diag) {
#pragma unroll
            for (int cc = 0; cc < 4; ++cc)
#pragma unroll
              for (int j = 0; j < 4; ++j) {
                int key = k0 + cc * 16 + lg * 4 + j;
                if (key > q) s[g][cc][j] = -3e38f;
              }
          }
          float lm = -3e38f;
#pragma unroll
          for (int cc = 0; cc < 4; ++cc)
#pragma unroll
            for (int j = 0; j < 4; ++j) lm = fmaxf(lm, s[g][cc][j]);
          if (__any(lm > m_s[g] + 8.f)) {   // rare: full reduce + rescale
            float pm = fmaxf(lm, __shfl_xor(lm, 16));
            pm = fmaxf(pm, __shfl_xor(pm, 32));
            float mn = fmaxf(m_s[g], pm);
            float fsc = fexp2(m_s[g] - mn);
#pragma unroll
            for (int j = 0; j < 4; ++j) {
              float fq = __shfl(fsc, lg * 4 + j);
#pragma unroll
              for (int n = 0; n < 5; ++n) oacc[g][n][j] *= fq;
            }
            m_s[g] = mn;
          }
#pragma unroll
          for (int cc = 0; cc < 4; ++cc)
#pragma unroll
            for (int j = 0; j < 4; ++j)
              s[g][cc][j] = fexp2(s[g][cc][j] - m_s[g]);
          // pack P^T -> per-wave LDS
#pragma unroll
          for (int cc = 0; cc < 4; ++cc)
#pragma unroll
            for (int jj = 0; jj < 4; jj += 2) {
              __hip_bfloat162 pr;
              pr.x = __float2bfloat16(s[g][cc][jj]);
              pr.y = __float2bfloat16(s[g][cc][jj + 1]);
              *(__hip_bfloat162*)&Pw[(g * 16 + lq) * 72 + cc * 16 + lg * 4 + jj] = pr;
            }
        }

        // --- PV: 16 MFMA + 4 ones-column MFMA (row sums) ---
#pragma unroll
        for (int c = 0; c < 2; ++c) {
          bfx8 pa[2];
#pragma unroll
          for (int g = 0; g < 2; ++g)
            pa[g] = *(const bfx8*)&Pw[(g * 16 + lq) * 72 + c * 32 + lg * 8];
          __builtin_amdgcn_s_setprio(1);
#pragma unroll
          for (int n = 0; n < 4; ++n) {
            bfx8 vf = *(const bfx8*)&Vlds[cur][n * 16 + lq][((c * 4 + lg) ^ (lq & 7)) << 3];
#pragma unroll
            for (int g = 0; g < 2; ++g)
              oacc[g][n] = __builtin_amdgcn_mfma_f32_16x16x32_bf16(pa[g], vf, oacc[g][n], 0, 0, 0);
          }
#pragma unroll
          for (int g = 0; g < 2; ++g)
            oacc[g][4] = __builtin_amdgcn_mfma_f32_16x16x32_bf16(pa[g], onesv, oacc[g][4], 0, 0, 0);
          __builtin_amdgcn_s_setprio(0);
        }
      }
      __syncthreads();   // drains staging vmcnt; publishes next K/V tiles
    }

    // --- normalize + write O[b][t][h*64 + d]; row-sum sits in oacc[g][4][j] ---
#pragma unroll
    for (int g = 0; g < 2; ++g)
#pragma unroll
      for (int j = 0; j < 4; ++j) {
        float linv = 1.f / oacc[g][4][j];
        int t = q_base + g * 16 + lg * 4 + j;
        size_t base = ((size_t)(b * Tt + t)) * Cm + h * DH;
#pragma unroll
        for (int n = 0; n < 4; ++n)
          O[base + n * 16 + lq] = (bf16)(oacc[g][n][j] * linv);
      }
    __syncthreads();   // LDS safe for next item's staging
#undef STAGE_KV
  }
}

extern "C" void kernel_launch(void* const* d_in, const int* in_sizes, int n_in,
                              void* d_out, int out_size, void* d_ws, size_t ws_size,
                              hipStream_t stream) {
  const float* x     = (const float*)d_in[0];
  const float* w_qkv = (const float*)d_in[1];
  const float* b_qkv = (const float*)d_in[2];
  const float* w_out = (const float*)d_in[3];
  const float* b_out = (const float*)d_in[4];
  float* out = (float*)d_out;

  const size_t MT = (size_t)Bb * Tt;  // 8192 rows
  bf16* ws    = (bf16*)d_ws;
  bf16* xb    = ws;                                  // 8Mi elems (x bf16; reused as attn out)
  bf16* attn  = xb;                                  // alias (dead after GEMM1)
  bf16* wqkvT = ws + MT * Cm;                        // 3Mi elems [3072][1024]
  bf16* woutT = wqkvT + (size_t)3 * Cm * Cm;         // 1Mi elems [1024][1024]
  bf16* Qb    = woutT + (size_t)Cm * Cm;             // 8Mi
  bf16* Kb    = Qb + (size_t)BH * Tt * DH;           // 8Mi
  bf16* Vtb   = Kb + (size_t)BH * Tt * DH;           // 8Mi

  // fused prep: cast (4096 blocks) + w_qkv^T (3072) + w_out^T (1024)
  prep_kernel<<<dim3(8192), 256, 0, stream>>>(x, xb, w_qkv, wqkvT, w_out, woutT);

  // QKV: proven round-7 config (128x128, 4 waves, single-buffer); grid 64x24
  gemm_tile<0, 128, 128, 2, 2><<<dim3(MT / 128, (3 * Cm) / 128), 256, 0, stream>>>(
      xb, wqkvT, b_qkv, nullptr, Qb, Kb, Vtb, (int)MT, 3 * Cm, Cm);

  // attn: round-7 champion config (512 blocks, exact-uniform, K+V staged)
  attn_fwd<<<dim3(512), 256, 0, stream>>>(Qb, Kb, Vtb, attn);

  // out-proj: proven 128x128 config; grid 64x8
  gemm_tile<1, 128, 128, 2, 2><<<dim3(MT / 128, Cm / 128), 256, 0, stream>>>(
      attn, woutT, b_out, out, nullptr, nullptr, nullptr, (int)MT, Cm, Cm);
}